// Round 16
// baseline (27387.564 us; speedup 1.0000x reference)
//
#include <hip/hip_runtime.h>
#include <hip/hip_fp16.h>

// MC-LSTM persistent recurrence, v17: v11 verbatim (8 b-slices x 7 unit-shards,
// 56 WGs x 512 thr, agent-relaxed tagged-data, dbuf slab, one slab hop + one
// norm hop per step) + two straggler-leveling deltas:
//   1. isO's out[] HBM writes deferred until AFTER the phase-6 slab publish
//      (removes their vmcnt drain from isO's B1 -> o-column publishes earlier).
//   2. norm compute+publish moved from isO to the us==0 WG (norm has phase-4
//      slack; slab columns gate phase 1 directly).

#define TT 2048
#define NBS 8
#define NUS 7
#define NWG 56

typedef _Float16 f16;
typedef _Float16 f16x8 __attribute__((ext_vector_type(8)));
typedef float f32x4 __attribute__((ext_vector_type(4)));

#define LD_RLX(p)   __hip_atomic_load((p), __ATOMIC_RELAXED, __HIP_MEMORY_SCOPE_AGENT)
#define ST_RLX(p,v) __hip_atomic_store((p), (v), __ATOMIC_RELAXED, __HIP_MEMORY_SCOPE_AGENT)

static __device__ __forceinline__ unsigned packf16(float v, unsigned tag) {
  f16 h = (f16)v;
  unsigned short s;
  __builtin_memcpy(&s, &h, 2);
  return ((unsigned)s << 16) | (tag & 0xffffu);
}
static __device__ __forceinline__ float unpackf16(unsigned u) {
  unsigned short s = (unsigned short)(u >> 16);
  f16 h;
  __builtin_memcpy(&h, &s, 2);
  return (float)h;
}
static __device__ __forceinline__ float f16bits(unsigned short s) {
  f16 h;
  __builtin_memcpy(&h, &s, 2);
  return (float)h;
}
static __device__ __forceinline__ unsigned short f16of(float v) {
  f16 h = (f16)v;
  unsigned short s;
  __builtin_memcpy(&s, &h, 2);
  return s;
}

// ---- ws layout (bytes) ----
#define OFF_WH   0u
#define SZ_WH    (97u * 8192u * 2u)                    // fp16 weights [unit][h][g]
#define OFF_SLAB ((OFF_WH + SZ_WH + 255u) & ~255u)     // [2][8 bs][7 us][1024] u32
#define SZ_SLAB  (2u * NBS * NUS * 1024u * 4u)
#define OFF_NS   (OFF_SLAB + SZ_SLAB)                  // [2][8 bs] tagged u32
#define SZ_NS    (2u * NBS * 4u)
#define ZERO_OFF OFF_SLAB
#define ZERO_LEN (SZ_SLAB + SZ_NS)

__global__ void prep_kernel(const float* __restrict__ Wi, const float* __restrict__ Wr,
                            const float* __restrict__ Wo, f16* __restrict__ Wh) {
  int idx = blockIdx.x * 256 + threadIdx.x;
  if (idx >= 97 * 8192) return;
  int g = idx & 127, h = (idx >> 7) & 63, r = idx >> 13;
  float v;
  if (r < 32)      v = Wi[g * 2048 + r * 64 + h];
  else if (r < 96) v = Wr[g * 4096 + (r - 32) * 64 + h];
  else             v = Wo[g * 64 + h];
  Wh[idx] = (f16)v;
}

__launch_bounds__(512, 1)
__global__ void mclstm_kernel(const float* __restrict__ xm, const float* __restrict__ xa,
                              const float* __restrict__ bi, const float* __restrict__ br,
                              const float* __restrict__ bo, const f16* __restrict__ Wh,
                              unsigned* __restrict__ slab, unsigned* __restrict__ nslab,
                              float* __restrict__ out) {
  const int j = blockIdx.x, tid = threadIdx.x;
  const int us = j % NUS, bs = j / NUS;
  const int w = tid >> 6, l = tid & 63, lr = l & 15, lk = l >> 4;
  const bool isO = (us == 6);
  const bool isNorm = (us == 0);  // norm duty moved OFF the o-column WG

  __shared__ unsigned short craw[16][88];  // raw c bits (this b-slice), padded rows
  __shared__ float pslab[8][1024];         // per-wave contrib partials
  __shared__ float nredL[8];
  __shared__ float invS;

  for (int i = tid; i < 16 * 88; i += 512) (&craw[0][0])[i] = 0;
  if (tid == 0) invS = 0.f;

  // ---- persistent weights in registers: 2 units per wave (us6 -> o unit 96) ----
  f16x8 Bf[2][4][4];
  float bu[2][4];
#pragma unroll
  for (int un = 0; un < 2; ++un) {
    int u = isO ? 96 : us * 16 + 2 * w + un;
#pragma unroll
    for (int ht = 0; ht < 4; ++ht) {
      int col = ht * 16 + lr;
      bu[un][ht] = (u < 32) ? bi[u * 64 + col]
                 : (u < 96) ? br[(u - 32) * 64 + col] : bo[col];
#pragma unroll
      for (int kk = 0; kk < 4; ++kk)
        Bf[un][ht][kk] = *(const f16x8*)(Wh + (size_t)u * 8192 + col * 128 + kk * 32 + lk * 8);
    }
  }

  const size_t xoff = (size_t)(bs * 16 + lr) * 32 + lk * 8;
  f32x4 xA0 = *(const f32x4*)(xm + xoff), xA1 = *(const f32x4*)(xm + xoff + 4);
  f32x4 xB0 = *(const f32x4*)(xa + xoff), xB1 = *(const f32x4*)(xa + xoff + 4);
  __syncthreads();

  for (int t = 0; t <= TT; ++t) {
    float mn0 = 0.f, mn1 = 0.f, ov0 = 0.f, ov1 = 0.f, cn0 = 0.f, cn1 = 0.f;

    // ---- phase 1: poll own b-slice slab (tag t); local reduce; stage craw ----
    if (t > 0) {
      const unsigned want = (unsigned)t & 0xffffu;
      const unsigned* base = slab + ((size_t)(t & 1) * NBS + bs) * (NUS * 1024);
      const int e0 = 2 * tid;
      unsigned pv[14];
      for (;;) {
#pragma unroll
        for (int c = 0; c < 7; ++c) {
          pv[c] = LD_RLX(base + c * 1024 + e0);
          pv[7 + c] = LD_RLX(base + c * 1024 + e0 + 1);
        }
        unsigned m = 0;
#pragma unroll
        for (int c = 0; c < 14; ++c) m |= (pv[c] ^ want) & 0xffffu;
        if (m == 0) break;
        __builtin_amdgcn_s_sleep(1);
      }
#pragma unroll
      for (int c = 0; c < 6; ++c) {
        mn0 += unpackf16(pv[c]);
        mn1 += unpackf16(pv[7 + c]);
      }
      ov0 = unpackf16(pv[6]);
      ov1 = unpackf16(pv[13]);
      cn0 = (1.0f - ov0) * mn0;
      cn1 = (1.0f - ov1) * mn1;
      const unsigned short h0 = f16of(cn0), h1 = f16of(cn1);
      const int b = e0 >> 6, h = e0 & 63;
      craw[b][h] = h0;
      craw[b][h + 1] = h1;
      if (isNorm) {
        // norm partial (from the f16-rounded c all WGs will use) -> publish fast
        float ns = fabsf(f16bits(h0)) + fabsf(f16bits(h1));
        ns += __shfl_xor(ns, 1, 64);
        ns += __shfl_xor(ns, 2, 64);
        ns += __shfl_xor(ns, 4, 64);
        ns += __shfl_xor(ns, 8, 64);
        ns += __shfl_xor(ns, 16, 64);
        ns += __shfl_xor(ns, 32, 64);
        if (l == 0) nredL[w] = ns;
        __syncthreads();
        if (tid == 0) {
          float nsum = 0.f;
#pragma unroll
          for (int p = 0; p < 8; ++p) nsum += nredL[p];
          ST_RLX(nslab + (t & 1) * NBS + bs, packf16(nsum, (unsigned)t));
        }
      }
    }
    if (t == TT) {
      if (isO) {  // final step's outputs (deferred-write pattern, at exit)
        const int e0 = 2 * tid, b = e0 >> 6, h = e0 & 63;
        const int bg = bs * 16 + b;
        out[(size_t)(t - 1) * 8192 + bg * 64 + h] = ov0 * mn0;
        out[(size_t)(t - 1) * 8192 + bg * 64 + h + 1] = ov1 * mn1;
        out[(size_t)(TT + t - 1) * 8192 + bg * 64 + h] = cn0;
        out[(size_t)(TT + t - 1) * 8192 + bg * 64 + h + 1] = cn1;
      }
      break;
    }
    __syncthreads();  // B1: craw staged

    // ---- phase 3: A-frags (raw c) + dual-accumulator GEMM ----
    f16x8 A0, A1, A2, A3;
#pragma unroll
    for (int i = 0; i < 4; ++i) {
      A0[i] = (f16)xA0[i]; A0[4 + i] = (f16)xA1[i];
      A1[i] = (f16)xB0[i]; A1[4 + i] = (f16)xB1[i];
    }
    {
      const unsigned short* cr = &craw[lr][0];
#pragma unroll
      for (int i = 0; i < 8; ++i) A2[i] = *(const f16*)&cr[lk * 8 + i];
#pragma unroll
      for (int i = 0; i < 8; ++i) A3[i] = *(const f16*)&cr[32 + lk * 8 + i];
    }
    if (t + 1 < TT) {
      const float* bx = xm + (size_t)(t + 1) * 4096 + xoff;
      const float* ba = xa + (size_t)(t + 1) * 4096 + xoff;
      xA0 = *(const f32x4*)bx; xA1 = *(const f32x4*)(bx + 4);
      xB0 = *(const f32x4*)ba; xB1 = *(const f32x4*)(ba + 4);
    }
    f32x4 aX[2][4], aC[2][4];
    if (!isO || w == 0) {
#pragma unroll
      for (int un = 0; un < 2; ++un)
#pragma unroll
        for (int ht = 0; ht < 4; ++ht) {
          f32x4 a = (f32x4){0.f, 0.f, 0.f, 0.f};
          a = __builtin_amdgcn_mfma_f32_16x16x32_f16(A0, Bf[un][ht][0], a, 0, 0, 0);
          a = __builtin_amdgcn_mfma_f32_16x16x32_f16(A1, Bf[un][ht][1], a, 0, 0, 0);
          aX[un][ht] = a;
          f32x4 c = (f32x4){0.f, 0.f, 0.f, 0.f};
          c = __builtin_amdgcn_mfma_f32_16x16x32_f16(A2, Bf[un][ht][2], c, 0, 0, 0);
          c = __builtin_amdgcn_mfma_f32_16x16x32_f16(A3, Bf[un][ht][3], c, 0, 0, 0);
          aC[un][ht] = c;
        }
    }

    // ---- phase 4: wave0 polls the 8 norm words (overlapped with GEMM above) ----
    if (t > 0 && w == 0) {
      const unsigned want = (unsigned)t & 0xffffu;
      const unsigned* nsb = nslab + (t & 1) * NBS;
      unsigned v;
      for (;;) {
        v = (l < NBS) ? LD_RLX(nsb + l) : want;
        if (__all((int)((v & 0xffffu) == want))) break;
        __builtin_amdgcn_s_sleep(1);
      }
      float ns = (l < NBS) ? unpackf16(v) : 0.f;
      ns += __shfl_xor(ns, 1, 64);
      ns += __shfl_xor(ns, 2, 64);
      ns += __shfl_xor(ns, 4, 64);
      if (l == 0) invS = __builtin_amdgcn_rcpf(ns + 1e-5f);
    }
    __syncthreads();  // B2: invS visible
    const float inv = invS;

    // ---- phase 5: epilogue z = aX + inv*aC + b ----
    if (!isO) {
      const float* xmtp = xm + (size_t)t * 4096;
      float contrib[4][4];
#pragma unroll
      for (int ht = 0; ht < 4; ++ht)
#pragma unroll
        for (int rr = 0; rr < 4; ++rr) contrib[ht][rr] = 0.f;
#pragma unroll
      for (int un = 0; un < 2; ++un) {
        const int u = us * 16 + 2 * w + un;
        const bool isI = (u < 32);
        const int kidx = u - 32;
#pragma unroll
        for (int rr = 0; rr < 4; ++rr) {
          const int b = lk * 4 + rr;
          float s4[4], sum = 0.f;
#pragma unroll
          for (int ht = 0; ht < 4; ++ht) {
            float z = aX[un][ht][rr] + inv * aC[un][ht][rr] + bu[un][ht];
            float sg = __builtin_amdgcn_rcpf(1.0f + __expf(-z));
            s4[ht] = sg;
            sum += sg;
          }
          float r4 = sum;
          r4 += __shfl_xor(r4, 1, 64);
          r4 += __shfl_xor(r4, 2, 64);
          r4 += __shfl_xor(r4, 4, 64);
          r4 += __shfl_xor(r4, 8, 64);
          float wr = isI ? xmtp[(size_t)(bs * 16 + b) * 32 + u] : f16bits(craw[b][kidx]);
          float sc = wr * __builtin_amdgcn_rcpf(fmaxf(r4, 1e-12f));
#pragma unroll
          for (int ht = 0; ht < 4; ++ht) contrib[ht][rr] += s4[ht] * sc;
        }
      }
#pragma unroll
      for (int ht = 0; ht < 4; ++ht)
#pragma unroll
        for (int rr = 0; rr < 4; ++rr)
          pslab[w][(lk * 4 + rr) * 64 + ht * 16 + lr] = contrib[ht][rr];
    } else if (w == 0) {
#pragma unroll
      for (int ht = 0; ht < 4; ++ht)
#pragma unroll
        for (int rr = 0; rr < 4; ++rr) {
          float z = aX[0][ht][rr] + inv * aC[0][ht][rr] + bu[0][ht];
          pslab[0][(lk * 4 + rr) * 64 + ht * 16 + lr] =
              __builtin_amdgcn_rcpf(1.0f + __expf(-z));
        }
    }
    __syncthreads();  // B3: pslab complete

    // ---- phase 6: intra-WG sum -> coalesced tagged column store (FIRST) ----
    {
      const int e0 = 2 * tid;
      float v0, v1;
      if (!isO) {
        v0 = 0.f; v1 = 0.f;
#pragma unroll
        for (int p = 0; p < 8; ++p) {
          float2 pv2 = *(const float2*)&pslab[p][e0];
          v0 += pv2.x;
          v1 += pv2.y;
        }
      } else {
        float2 pv2 = *(const float2*)&pslab[0][e0];
        v0 = pv2.x;
        v1 = pv2.y;
      }
      const unsigned tg = (unsigned)(t + 1);
      unsigned* dst = slab + ((size_t)((t + 1) & 1) * NBS + bs) * (NUS * 1024) + us * 1024;
      ST_RLX(dst + e0, packf16(v0, tg));
      ST_RLX(dst + e0 + 1, packf16(v1, tg));
    }
    __syncthreads();  // B4: WAR (craw reads in phase 5 vs next phase-1 writes)

    // ---- phase 7: out[] for step t-1 — AFTER slab publish (isO, contiguous).
    // Drain overlaps the next step's poll instead of gating isO's B1.
    if (t > 0 && isO) {
      const int e0 = 2 * tid, b = e0 >> 6, h = e0 & 63;
      const int bg = bs * 16 + b;
      out[(size_t)(t - 1) * 8192 + bg * 64 + h] = ov0 * mn0;
      out[(size_t)(t - 1) * 8192 + bg * 64 + h + 1] = ov1 * mn1;
      out[(size_t)(TT + t - 1) * 8192 + bg * 64 + h] = cn0;
      out[(size_t)(TT + t - 1) * 8192 + bg * 64 + h + 1] = cn1;
    }
  }
}

extern "C" void kernel_launch(void* const* d_in, const int* in_sizes, int n_in,
                              void* d_out, int out_size, void* d_ws, size_t ws_size,
                              hipStream_t stream) {
  (void)in_sizes; (void)n_in; (void)out_size; (void)ws_size;
  const float* xm = (const float*)d_in[0];
  const float* xa = (const float*)d_in[1];
  const float* Wi = (const float*)d_in[2];
  const float* bi = (const float*)d_in[3];
  const float* Wr = (const float*)d_in[4];
  const float* br = (const float*)d_in[5];
  const float* Wo = (const float*)d_in[6];
  const float* bo = (const float*)d_in[7];

  char* ws = (char*)d_ws;
  f16* Wh         = (f16*)(ws + OFF_WH);
  unsigned* slab  = (unsigned*)(ws + OFF_SLAB);
  unsigned* nslab = (unsigned*)(ws + OFF_NS);

  // Tag hygiene across graph replays.
  hipMemsetAsync(ws + ZERO_OFF, 0, ZERO_LEN, stream);
  prep_kernel<<<(97 * 8192 + 255) / 256, 256, 0, stream>>>(Wi, Wr, Wo, Wh);
  mclstm_kernel<<<NWG, 512, 0, stream>>>(xm, xa, bi, br, bo, Wh, slab, nslab,
                                         (float*)d_out);
}

// Round 17
// 23594.109 us; speedup vs baseline: 1.1608x; 1.1608x over previous
//
#include <hip/hip_runtime.h>
#include <hip/hip_fp16.h>

// MC-LSTM persistent recurrence, v18: v11 EXACT topology/ordering (champion,
// 17.65 ms) + fail-safe single-XCD fast path:
//  - workers claimed onto XCD 0 (XCC_ID + agent atomic; bounded-timeout
//    fallback lets any block claim unfilled slots -> no missing workers),
//  - every cross-WG word dual-published (sc0 -> local L2, agent -> MALL),
//  - every poll alternates sc0 sweep (fast, same-XCD) with agent sweep
//    (liveness). Tag check makes either path correctness-equivalent.

#define TT 2048
#define NBS 8
#define NUS 7
#define NWG 56
#define GRID 2048

typedef _Float16 f16;
typedef _Float16 f16x8 __attribute__((ext_vector_type(8)));
typedef float f32x4 __attribute__((ext_vector_type(4)));

#define LD_RLX(p)   __hip_atomic_load((p), __ATOMIC_RELAXED, __HIP_MEMORY_SCOPE_AGENT)
#define ST_RLX(p,v) __hip_atomic_store((p), (v), __ATOMIC_RELAXED, __HIP_MEMORY_SCOPE_AGENT)

static __device__ __forceinline__ unsigned packf16(float v, unsigned tag) {
  f16 h = (f16)v;
  unsigned short s;
  __builtin_memcpy(&s, &h, 2);
  return ((unsigned)s << 16) | (tag & 0xffffu);
}
static __device__ __forceinline__ float unpackf16(unsigned u) {
  unsigned short s = (unsigned short)(u >> 16);
  f16 h;
  __builtin_memcpy(&h, &s, 2);
  return (float)h;
}
static __device__ __forceinline__ float f16bits(unsigned short s) {
  f16 h;
  __builtin_memcpy(&h, &s, 2);
  return (float)h;
}
static __device__ __forceinline__ unsigned short f16of(float v) {
  f16 h = (f16)v;
  unsigned short s;
  __builtin_memcpy(&s, &h, 2);
  return s;
}

// ---- sc0 (L1-bypass, L2-served) primitives: fast path only; liveness never
// depends on them (agent sweep in every poll iteration). ----
static __device__ __forceinline__ unsigned ld_sc0(const unsigned* p) {
  unsigned v;
  asm volatile("global_load_dword %0, %1, off sc0\n\ts_waitcnt vmcnt(0)"
               : "=v"(v) : "v"(p) : "memory");
  return v;
}
static __device__ __forceinline__ void st_sc0(unsigned* p, unsigned v) {
  asm volatile("global_store_dword %0, %1, off sc0" :: "v"(p), "v"(v) : "memory");
}
static __device__ __forceinline__ void sweep14_sc0(const unsigned* base, int e0,
                                                   unsigned pv[14]) {
  const unsigned* p0 = base + e0;
  const unsigned* p1 = base + 1024 + e0;
  const unsigned* p2 = base + 2048 + e0;
  const unsigned* p3 = base + 3072 + e0;
  const unsigned* p4 = base + 4096 + e0;
  const unsigned* p5 = base + 5120 + e0;
  const unsigned* p6 = base + 6144 + e0;
  asm volatile(
      "global_load_dword %0, %14, off sc0\n\t"
      "global_load_dword %7, %14, off offset:4 sc0\n\t"
      "global_load_dword %1, %15, off sc0\n\t"
      "global_load_dword %8, %15, off offset:4 sc0\n\t"
      "global_load_dword %2, %16, off sc0\n\t"
      "global_load_dword %9, %16, off offset:4 sc0\n\t"
      "global_load_dword %3, %17, off sc0\n\t"
      "global_load_dword %10, %17, off offset:4 sc0\n\t"
      "global_load_dword %4, %18, off sc0\n\t"
      "global_load_dword %11, %18, off offset:4 sc0\n\t"
      "global_load_dword %5, %19, off sc0\n\t"
      "global_load_dword %12, %19, off offset:4 sc0\n\t"
      "global_load_dword %6, %20, off sc0\n\t"
      "global_load_dword %13, %20, off offset:4 sc0\n\t"
      "s_waitcnt vmcnt(0)"
      : "=&v"(pv[0]), "=&v"(pv[1]), "=&v"(pv[2]), "=&v"(pv[3]), "=&v"(pv[4]),
        "=&v"(pv[5]), "=&v"(pv[6]), "=&v"(pv[7]), "=&v"(pv[8]), "=&v"(pv[9]),
        "=&v"(pv[10]), "=&v"(pv[11]), "=&v"(pv[12]), "=&v"(pv[13])
      : "v"(p0), "v"(p1), "v"(p2), "v"(p3), "v"(p4), "v"(p5), "v"(p6)
      : "memory");
}

// ---- ws layout (bytes) ----
#define OFF_WH    0u
#define SZ_WH     (97u * 8192u * 2u)                   // fp16 weights [unit][h][g]
#define OFF_SLAB  ((OFF_WH + SZ_WH + 255u) & ~255u)    // [2][8 bs][7 us][1024] u32
#define SZ_SLAB   (2u * NBS * NUS * 1024u * 4u)
#define OFF_NS    (OFF_SLAB + SZ_SLAB)                 // [2][8 bs] tagged u32
#define SZ_NS     (2u * NBS * 4u)
#define OFF_CLAIM ((OFF_NS + SZ_NS + 255u) & ~255u)
#define ZERO_OFF  OFF_SLAB
#define ZERO_LEN  (OFF_CLAIM - OFF_SLAB + 256u)

__global__ void prep_kernel(const float* __restrict__ Wi, const float* __restrict__ Wr,
                            const float* __restrict__ Wo, f16* __restrict__ Wh) {
  int idx = blockIdx.x * 256 + threadIdx.x;
  if (idx >= 97 * 8192) return;
  int g = idx & 127, h = (idx >> 7) & 63, r = idx >> 13;
  float v;
  if (r < 32)      v = Wi[g * 2048 + r * 64 + h];
  else if (r < 96) v = Wr[g * 4096 + (r - 32) * 64 + h];
  else             v = Wo[g * 64 + h];
  Wh[idx] = (f16)v;
}

__launch_bounds__(512, 1)
__global__ void mclstm_kernel(const float* __restrict__ xm, const float* __restrict__ xa,
                              const float* __restrict__ bi, const float* __restrict__ br,
                              const float* __restrict__ bo, const f16* __restrict__ Wh,
                              unsigned* __restrict__ slab, unsigned* __restrict__ nslab,
                              unsigned* __restrict__ claim, float* __restrict__ out) {
  const int tid = threadIdx.x;
  __shared__ int slotS;

  // ---- claim a worker slot; prefer XCD 0 (bounded fallback: never a hole) ----
  if (tid == 0) {
    unsigned xcc;
    asm("s_getreg_b32 %0, hwreg(HW_REG_XCC_ID)" : "=s"(xcc));
    int s = -1;
    if (xcc == 0) {
      s = (int)__hip_atomic_fetch_add(claim, 1u, __ATOMIC_RELAXED,
                                      __HIP_MEMORY_SCOPE_AGENT);
    } else {
      // wait a bounded time for XCD0 blocks to fill the slots; if still short,
      // claim anyway (degenerates to v11's multi-XCD placement, still correct).
      for (int it = 0; it < (1 << 14); ++it) {
        if (LD_RLX(claim) >= (unsigned)NWG) break;
        __builtin_amdgcn_s_sleep(4);
      }
      if (LD_RLX(claim) < (unsigned)NWG)
        s = (int)__hip_atomic_fetch_add(claim, 1u, __ATOMIC_RELAXED,
                                        __HIP_MEMORY_SCOPE_AGENT);
    }
    slotS = s;
  }
  __syncthreads();
  const int slot = slotS;
  if (slot < 0 || slot >= NWG) return;

  const int us = slot % NUS, bs = slot / NUS;
  const int w = tid >> 6, l = tid & 63, lr = l & 15, lk = l >> 4;
  const bool isO = (us == 6);

  __shared__ unsigned short craw[16][88];  // raw c bits (this b-slice), padded rows
  __shared__ float pslab[8][1024];         // per-wave contrib partials
  __shared__ float nredL[8];
  __shared__ float invS;

  for (int i = tid; i < 16 * 88; i += 512) (&craw[0][0])[i] = 0;
  if (tid == 0) invS = 0.f;

  // ---- persistent weights: 2 units per wave (us6 -> o unit 96) ----
  f16x8 Bf[2][4][4];
  float bu[2][4];
#pragma unroll
  for (int un = 0; un < 2; ++un) {
    int u = isO ? 96 : us * 16 + 2 * w + un;
#pragma unroll
    for (int ht = 0; ht < 4; ++ht) {
      int col = ht * 16 + lr;
      bu[un][ht] = (u < 32) ? bi[u * 64 + col]
                 : (u < 96) ? br[(u - 32) * 64 + col] : bo[col];
#pragma unroll
      for (int kk = 0; kk < 4; ++kk)
        Bf[un][ht][kk] = *(const f16x8*)(Wh + (size_t)u * 8192 + col * 128 + kk * 32 + lk * 8);
    }
  }

  const size_t xoff = (size_t)(bs * 16 + lr) * 32 + lk * 8;
  f32x4 xA0 = *(const f32x4*)(xm + xoff), xA1 = *(const f32x4*)(xm + xoff + 4);
  f32x4 xB0 = *(const f32x4*)(xa + xoff), xB1 = *(const f32x4*)(xa + xoff + 4);
  __syncthreads();

  for (int t = 0; t <= TT; ++t) {
    // ---- phase 1: poll own b-slice slab (tag t); local reduce; stage craw ----
    if (t > 0) {
      const unsigned want = (unsigned)t & 0xffffu;
      const unsigned* base = slab + ((size_t)(t & 1) * NBS + bs) * (NUS * 1024);
      const int e0 = 2 * tid;
      unsigned pv[14];
      for (;;) {
        // fast path: sc0 sweep (same-XCD L2)
        sweep14_sc0(base, e0, pv);
        unsigned m = 0;
#pragma unroll
        for (int c = 0; c < 14; ++c) m |= (pv[c] ^ want) & 0xffffu;
        if (m == 0) break;
        // liveness path: agent sweep (MALL)
#pragma unroll
        for (int c = 0; c < 7; ++c) {
          pv[c] = LD_RLX(base + c * 1024 + e0);
          pv[7 + c] = LD_RLX(base + c * 1024 + e0 + 1);
        }
        m = 0;
#pragma unroll
        for (int c = 0; c < 14; ++c) m |= (pv[c] ^ want) & 0xffffu;
        if (m == 0) break;
        __builtin_amdgcn_s_sleep(1);
      }
      float mn0 = 0.f, mn1 = 0.f;
#pragma unroll
      for (int c = 0; c < 6; ++c) {
        mn0 += unpackf16(pv[c]);
        mn1 += unpackf16(pv[7 + c]);
      }
      const float ov0 = unpackf16(pv[6]), ov1 = unpackf16(pv[13]);
      const float cn0 = (1.0f - ov0) * mn0, cn1 = (1.0f - ov1) * mn1;
      const unsigned short h0 = f16of(cn0), h1 = f16of(cn1);
      const int b = e0 >> 6, h = e0 & 63;
      craw[b][h] = h0;
      craw[b][h + 1] = h1;
      if (isO) {
        // norm partial (from the f16-rounded c all WGs will use) -> publish fast
        float ns = fabsf(f16bits(h0)) + fabsf(f16bits(h1));
        ns += __shfl_xor(ns, 1, 64);
        ns += __shfl_xor(ns, 2, 64);
        ns += __shfl_xor(ns, 4, 64);
        ns += __shfl_xor(ns, 8, 64);
        ns += __shfl_xor(ns, 16, 64);
        ns += __shfl_xor(ns, 32, 64);
        if (l == 0) nredL[w] = ns;
        __syncthreads();
        if (tid == 0) {
          float nsum = 0.f;
#pragma unroll
          for (int p = 0; p < 8; ++p) nsum += nredL[p];
          unsigned nv = packf16(nsum, (unsigned)t);
          unsigned* np = nslab + (t & 1) * NBS + bs;
          st_sc0(np, nv);   // fast path (local L2)
          ST_RLX(np, nv);   // liveness path (MALL)
        }
        // out writes for step t-1 (off critical path)
        const int bg = bs * 16 + b;
        out[(size_t)(t - 1) * 8192 + bg * 64 + h] = ov0 * mn0;
        out[(size_t)(t - 1) * 8192 + bg * 64 + h + 1] = ov1 * mn1;
        out[(size_t)(TT + t - 1) * 8192 + bg * 64 + h] = cn0;
        out[(size_t)(TT + t - 1) * 8192 + bg * 64 + h + 1] = cn1;
      }
    }
    if (t == TT) break;
    __syncthreads();  // B1: craw staged

    // ---- phase 3: A-frags (raw c) + dual-accumulator GEMM ----
    f16x8 A0, A1, A2, A3;
#pragma unroll
    for (int i = 0; i < 4; ++i) {
      A0[i] = (f16)xA0[i]; A0[4 + i] = (f16)xA1[i];
      A1[i] = (f16)xB0[i]; A1[4 + i] = (f16)xB1[i];
    }
    {
      const unsigned short* cr = &craw[lr][0];
#pragma unroll
      for (int i = 0; i < 8; ++i) A2[i] = *(const f16*)&cr[lk * 8 + i];
#pragma unroll
      for (int i = 0; i < 8; ++i) A3[i] = *(const f16*)&cr[32 + lk * 8 + i];
    }
    if (t + 1 < TT) {
      const float* bx = xm + (size_t)(t + 1) * 4096 + xoff;
      const float* ba = xa + (size_t)(t + 1) * 4096 + xoff;
      xA0 = *(const f32x4*)bx; xA1 = *(const f32x4*)(bx + 4);
      xB0 = *(const f32x4*)ba; xB1 = *(const f32x4*)(ba + 4);
    }
    f32x4 aX[2][4], aC[2][4];
    if (!isO || w == 0) {
#pragma unroll
      for (int un = 0; un < 2; ++un)
#pragma unroll
        for (int ht = 0; ht < 4; ++ht) {
          f32x4 a = (f32x4){0.f, 0.f, 0.f, 0.f};
          a = __builtin_amdgcn_mfma_f32_16x16x32_f16(A0, Bf[un][ht][0], a, 0, 0, 0);
          a = __builtin_amdgcn_mfma_f32_16x16x32_f16(A1, Bf[un][ht][1], a, 0, 0, 0);
          aX[un][ht] = a;
          f32x4 c = (f32x4){0.f, 0.f, 0.f, 0.f};
          c = __builtin_amdgcn_mfma_f32_16x16x32_f16(A2, Bf[un][ht][2], c, 0, 0, 0);
          c = __builtin_amdgcn_mfma_f32_16x16x32_f16(A3, Bf[un][ht][3], c, 0, 0, 0);
          aC[un][ht] = c;
        }
    }

    // ---- phase 4: wave0 polls the 8 norm words (overlapped with GEMM) ----
    if (t > 0 && w == 0) {
      const unsigned want = (unsigned)t & 0xffffu;
      const unsigned* nsb = nslab + (t & 1) * NBS;
      unsigned v = want;
      for (;;) {
        if (l < NBS) v = ld_sc0(nsb + l);           // fast path
        if (__all((int)((v & 0xffffu) == want))) break;
        if (l < NBS) v = LD_RLX(nsb + l);           // liveness path
        if (__all((int)((v & 0xffffu) == want))) break;
        __builtin_amdgcn_s_sleep(1);
      }
      float ns = (l < NBS) ? unpackf16(v) : 0.f;
      ns += __shfl_xor(ns, 1, 64);
      ns += __shfl_xor(ns, 2, 64);
      ns += __shfl_xor(ns, 4, 64);
      if (l == 0) invS = __builtin_amdgcn_rcpf(ns + 1e-5f);
    }
    __syncthreads();  // B2: invS visible
    const float inv = invS;

    // ---- phase 5: epilogue z = aX + inv*aC + b ----
    if (!isO) {
      const float* xmtp = xm + (size_t)t * 4096;
      float contrib[4][4];
#pragma unroll
      for (int ht = 0; ht < 4; ++ht)
#pragma unroll
        for (int rr = 0; rr < 4; ++rr) contrib[ht][rr] = 0.f;
#pragma unroll
      for (int un = 0; un < 2; ++un) {
        const int u = us * 16 + 2 * w + un;
        const bool isI = (u < 32);
        const int kidx = u - 32;
#pragma unroll
        for (int rr = 0; rr < 4; ++rr) {
          const int b = lk * 4 + rr;
          float s4[4], sum = 0.f;
#pragma unroll
          for (int ht = 0; ht < 4; ++ht) {
            float z = aX[un][ht][rr] + inv * aC[un][ht][rr] + bu[un][ht];
            float sg = __builtin_amdgcn_rcpf(1.0f + __expf(-z));
            s4[ht] = sg;
            sum += sg;
          }
          float r4 = sum;
          r4 += __shfl_xor(r4, 1, 64);
          r4 += __shfl_xor(r4, 2, 64);
          r4 += __shfl_xor(r4, 4, 64);
          r4 += __shfl_xor(r4, 8, 64);
          float wr = isI ? xmtp[(size_t)(bs * 16 + b) * 32 + u] : f16bits(craw[b][kidx]);
          float sc = wr * __builtin_amdgcn_rcpf(fmaxf(r4, 1e-12f));
#pragma unroll
          for (int ht = 0; ht < 4; ++ht) contrib[ht][rr] += s4[ht] * sc;
        }
      }
#pragma unroll
      for (int ht = 0; ht < 4; ++ht)
#pragma unroll
        for (int rr = 0; rr < 4; ++rr)
          pslab[w][(lk * 4 + rr) * 64 + ht * 16 + lr] = contrib[ht][rr];
    } else if (w == 0) {
#pragma unroll
      for (int ht = 0; ht < 4; ++ht)
#pragma unroll
        for (int rr = 0; rr < 4; ++rr) {
          float z = aX[0][ht][rr] + inv * aC[0][ht][rr] + bu[0][ht];
          pslab[0][(lk * 4 + rr) * 64 + ht * 16 + lr] =
              __builtin_amdgcn_rcpf(1.0f + __expf(-z));
        }
    }
    __syncthreads();  // B3: pslab complete

    // ---- phase 6: intra-WG sum -> tagged column store, DUAL-published ----
    {
      const int e0 = 2 * tid;
      float v0, v1;
      if (!isO) {
        v0 = 0.f; v1 = 0.f;
#pragma unroll
        for (int p = 0; p < 8; ++p) {
          float2 pv2 = *(const float2*)&pslab[p][e0];
          v0 += pv2.x;
          v1 += pv2.y;
        }
      } else {
        float2 pv2 = *(const float2*)&pslab[0][e0];
        v0 = pv2.x;
        v1 = pv2.y;
      }
      const unsigned tg = (unsigned)(t + 1);
      unsigned* dst = slab + ((size_t)((t + 1) & 1) * NBS + bs) * (NUS * 1024) + us * 1024;
      const unsigned q0 = packf16(v0, tg), q1 = packf16(v1, tg);
      st_sc0(dst + e0, q0);       // fast path (local L2)
      st_sc0(dst + e0 + 1, q1);
      ST_RLX(dst + e0, q0);       // liveness path (MALL)
      ST_RLX(dst + e0 + 1, q1);
    }
    __syncthreads();  // B4: WAR (craw reads in phase 5 vs next phase-1 writes)
  }
}

extern "C" void kernel_launch(void* const* d_in, const int* in_sizes, int n_in,
                              void* d_out, int out_size, void* d_ws, size_t ws_size,
                              hipStream_t stream) {
  (void)in_sizes; (void)n_in; (void)out_size; (void)ws_size;
  const float* xm = (const float*)d_in[0];
  const float* xa = (const float*)d_in[1];
  const float* Wi = (const float*)d_in[2];
  const float* bi = (const float*)d_in[3];
  const float* Wr = (const float*)d_in[4];
  const float* br = (const float*)d_in[5];
  const float* Wo = (const float*)d_in[6];
  const float* bo = (const float*)d_in[7];

  char* ws = (char*)d_ws;
  f16* Wh         = (f16*)(ws + OFF_WH);
  unsigned* slab  = (unsigned*)(ws + OFF_SLAB);
  unsigned* nslab = (unsigned*)(ws + OFF_NS);
  unsigned* claim = (unsigned*)(ws + OFF_CLAIM);

  // Per-launch hygiene: tags + claim counter (graph replays reuse ws).
  hipMemsetAsync(ws + ZERO_OFF, 0, ZERO_LEN, stream);
  prep_kernel<<<(97 * 8192 + 255) / 256, 256, 0, stream>>>(Wi, Wr, Wo, Wh);
  mclstm_kernel<<<GRID, 512, 0, stream>>>(xm, xa, bi, br, bo, Wh, slab, nslab,
                                          claim, (float*)d_out);
}

// Round 18
// 17717.860 us; speedup vs baseline: 1.5458x; 1.3317x over previous
//
#include <hip/hip_runtime.h>
#include <hip/hip_fp16.h>

// MC-LSTM persistent recurrence, FINAL (= v11, the measured champion at
// 17.65 ms): 8 b-slices x 7 unit-shards (56 WGs x 512 thr). ONE cross-WG slab
// hop + one norm hop per step: double-buffered tagged slab
// ([slot][bs][us][1024], col-major coalesced); every WG redundantly reduces
// its OWN b-slice (c never crosses WGs). Scalar L1 norm published as 8 tagged
// words and consumed LATE: GEMM runs on raw c, inv applied in the epilogue
// (z = accX + inv*accC + b).
//
// Survived-falsified alternatives (rounds 2-17): atomic-RMW barriers, flag
// arrays, release/acquire flavors, fp16 vs f32 payloads, sentinel gating,
// phase reordering, out[]-store deferral, democratized norm, single-XCD sc0
// sync (stale-L2 lines -> invalid mechanism). v11's ordering is a sharp
// local optimum; period = ~2.6us compute + 2 MALL rendezvous + straggler
// spread of 56 WGs, with WG count pinned by VGPR weight residency.

#define TT 2048
#define NBS 8
#define NUS 7
#define NWG 56

typedef _Float16 f16;
typedef _Float16 f16x8 __attribute__((ext_vector_type(8)));
typedef float f32x4 __attribute__((ext_vector_type(4)));

#define LD_RLX(p)   __hip_atomic_load((p), __ATOMIC_RELAXED, __HIP_MEMORY_SCOPE_AGENT)
#define ST_RLX(p,v) __hip_atomic_store((p), (v), __ATOMIC_RELAXED, __HIP_MEMORY_SCOPE_AGENT)

static __device__ __forceinline__ unsigned packf16(float v, unsigned tag) {
  f16 h = (f16)v;
  unsigned short s;
  __builtin_memcpy(&s, &h, 2);
  return ((unsigned)s << 16) | (tag & 0xffffu);
}
static __device__ __forceinline__ float unpackf16(unsigned u) {
  unsigned short s = (unsigned short)(u >> 16);
  f16 h;
  __builtin_memcpy(&h, &s, 2);
  return (float)h;
}
static __device__ __forceinline__ float f16bits(unsigned short s) {
  f16 h;
  __builtin_memcpy(&h, &s, 2);
  return (float)h;
}
static __device__ __forceinline__ unsigned short f16of(float v) {
  f16 h = (f16)v;
  unsigned short s;
  __builtin_memcpy(&s, &h, 2);
  return s;
}

// ---- ws layout (bytes) ----
#define OFF_WH   0u
#define SZ_WH    (97u * 8192u * 2u)                    // fp16 weights [unit][h][g]
#define OFF_SLAB ((OFF_WH + SZ_WH + 255u) & ~255u)     // [2][8 bs][7 us][1024] u32
#define SZ_SLAB  (2u * NBS * NUS * 1024u * 4u)
#define OFF_NS   (OFF_SLAB + SZ_SLAB)                  // [2][8 bs] tagged u32
#define SZ_NS    (2u * NBS * 4u)
#define ZERO_OFF OFF_SLAB
#define ZERO_LEN (SZ_SLAB + SZ_NS)

__global__ void prep_kernel(const float* __restrict__ Wi, const float* __restrict__ Wr,
                            const float* __restrict__ Wo, f16* __restrict__ Wh) {
  int idx = blockIdx.x * 256 + threadIdx.x;
  if (idx >= 97 * 8192) return;
  int g = idx & 127, h = (idx >> 7) & 63, r = idx >> 13;
  float v;
  if (r < 32)      v = Wi[g * 2048 + r * 64 + h];
  else if (r < 96) v = Wr[g * 4096 + (r - 32) * 64 + h];
  else             v = Wo[g * 64 + h];
  Wh[idx] = (f16)v;
}

__launch_bounds__(512, 1)
__global__ void mclstm_kernel(const float* __restrict__ xm, const float* __restrict__ xa,
                              const float* __restrict__ bi, const float* __restrict__ br,
                              const float* __restrict__ bo, const f16* __restrict__ Wh,
                              unsigned* __restrict__ slab, unsigned* __restrict__ nslab,
                              float* __restrict__ out) {
  const int j = blockIdx.x, tid = threadIdx.x;
  const int us = j % NUS, bs = j / NUS;
  const int w = tid >> 6, l = tid & 63, lr = l & 15, lk = l >> 4;
  const bool isO = (us == 6);

  __shared__ unsigned short craw[16][88];  // raw c bits (this b-slice), padded rows
  __shared__ float pslab[8][1024];         // per-wave contrib partials
  __shared__ float nredL[8];
  __shared__ float invS;

  for (int i = tid; i < 16 * 88; i += 512) (&craw[0][0])[i] = 0;
  if (tid == 0) invS = 0.f;

  // ---- persistent weights in registers: 2 units per wave (us6 -> o unit 96) ----
  f16x8 Bf[2][4][4];
  float bu[2][4];
#pragma unroll
  for (int un = 0; un < 2; ++un) {
    int u = isO ? 96 : us * 16 + 2 * w + un;
#pragma unroll
    for (int ht = 0; ht < 4; ++ht) {
      int col = ht * 16 + lr;
      bu[un][ht] = (u < 32) ? bi[u * 64 + col]
                 : (u < 96) ? br[(u - 32) * 64 + col] : bo[col];
#pragma unroll
      for (int kk = 0; kk < 4; ++kk)
        Bf[un][ht][kk] = *(const f16x8*)(Wh + (size_t)u * 8192 + col * 128 + kk * 32 + lk * 8);
    }
  }

  const size_t xoff = (size_t)(bs * 16 + lr) * 32 + lk * 8;
  f32x4 xA0 = *(const f32x4*)(xm + xoff), xA1 = *(const f32x4*)(xm + xoff + 4);
  f32x4 xB0 = *(const f32x4*)(xa + xoff), xB1 = *(const f32x4*)(xa + xoff + 4);
  __syncthreads();

  for (int t = 0; t <= TT; ++t) {
    // ---- phase 1: poll own b-slice slab (tag t); local reduce; stage craw ----
    if (t > 0) {
      const unsigned want = (unsigned)t & 0xffffu;
      const unsigned* base = slab + ((size_t)(t & 1) * NBS + bs) * (NUS * 1024);
      const int e0 = 2 * tid;
      unsigned pv[14];
      for (;;) {
#pragma unroll
        for (int c = 0; c < 7; ++c) {
          pv[c] = LD_RLX(base + c * 1024 + e0);
          pv[7 + c] = LD_RLX(base + c * 1024 + e0 + 1);
        }
        unsigned m = 0;
#pragma unroll
        for (int c = 0; c < 14; ++c) m |= (pv[c] ^ want) & 0xffffu;
        if (m == 0) break;
        __builtin_amdgcn_s_sleep(1);
      }
      float mn0 = 0.f, mn1 = 0.f;
#pragma unroll
      for (int c = 0; c < 6; ++c) {
        mn0 += unpackf16(pv[c]);
        mn1 += unpackf16(pv[7 + c]);
      }
      const float ov0 = unpackf16(pv[6]), ov1 = unpackf16(pv[13]);
      const float cn0 = (1.0f - ov0) * mn0, cn1 = (1.0f - ov1) * mn1;
      const unsigned short h0 = f16of(cn0), h1 = f16of(cn1);
      const int b = e0 >> 6, h = e0 & 63;
      craw[b][h] = h0;
      craw[b][h + 1] = h1;
      if (isO) {
        // norm partial (from the f16-rounded c all WGs will use) -> publish fast
        float ns = fabsf(f16bits(h0)) + fabsf(f16bits(h1));
        ns += __shfl_xor(ns, 1, 64);
        ns += __shfl_xor(ns, 2, 64);
        ns += __shfl_xor(ns, 4, 64);
        ns += __shfl_xor(ns, 8, 64);
        ns += __shfl_xor(ns, 16, 64);
        ns += __shfl_xor(ns, 32, 64);
        if (l == 0) nredL[w] = ns;
        __syncthreads();
        if (tid == 0) {
          float nsum = 0.f;
#pragma unroll
          for (int p = 0; p < 8; ++p) nsum += nredL[p];
          ST_RLX(nslab + (t & 1) * NBS + bs, packf16(nsum, (unsigned)t));
        }
        // out writes for step t-1 (off critical path)
        const int bg = bs * 16 + b;
        out[(size_t)(t - 1) * 8192 + bg * 64 + h] = ov0 * mn0;
        out[(size_t)(t - 1) * 8192 + bg * 64 + h + 1] = ov1 * mn1;
        out[(size_t)(TT + t - 1) * 8192 + bg * 64 + h] = cn0;
        out[(size_t)(TT + t - 1) * 8192 + bg * 64 + h + 1] = cn1;
      }
    }
    if (t == TT) break;
    __syncthreads();  // B1: craw staged

    // ---- phase 3: A-frags (raw c, NO inv) + dual-accumulator GEMM ----
    f16x8 A0, A1, A2, A3;
#pragma unroll
    for (int i = 0; i < 4; ++i) {
      A0[i] = (f16)xA0[i]; A0[4 + i] = (f16)xA1[i];
      A1[i] = (f16)xB0[i]; A1[4 + i] = (f16)xB1[i];
    }
    {
      const unsigned short* cr = &craw[lr][0];
#pragma unroll
      for (int i = 0; i < 8; ++i) A2[i] = *(const f16*)&cr[lk * 8 + i];
#pragma unroll
      for (int i = 0; i < 8; ++i) A3[i] = *(const f16*)&cr[32 + lk * 8 + i];
    }
    if (t + 1 < TT) {
      const float* bx = xm + (size_t)(t + 1) * 4096 + xoff;
      const float* ba = xa + (size_t)(t + 1) * 4096 + xoff;
      xA0 = *(const f32x4*)bx; xA1 = *(const f32x4*)(bx + 4);
      xB0 = *(const f32x4*)ba; xB1 = *(const f32x4*)(ba + 4);
    }
    f32x4 aX[2][4], aC[2][4];
    if (!isO || w == 0) {
#pragma unroll
      for (int un = 0; un < 2; ++un)
#pragma unroll
        for (int ht = 0; ht < 4; ++ht) {
          f32x4 a = (f32x4){0.f, 0.f, 0.f, 0.f};
          a = __builtin_amdgcn_mfma_f32_16x16x32_f16(A0, Bf[un][ht][0], a, 0, 0, 0);
          a = __builtin_amdgcn_mfma_f32_16x16x32_f16(A1, Bf[un][ht][1], a, 0, 0, 0);
          aX[un][ht] = a;
          f32x4 c = (f32x4){0.f, 0.f, 0.f, 0.f};
          c = __builtin_amdgcn_mfma_f32_16x16x32_f16(A2, Bf[un][ht][2], c, 0, 0, 0);
          c = __builtin_amdgcn_mfma_f32_16x16x32_f16(A3, Bf[un][ht][3], c, 0, 0, 0);
          aC[un][ht] = c;
        }
    }

    // ---- phase 4: wave0 polls the 8 norm words (overlapped with GEMM above) ----
    if (t > 0 && w == 0) {
      const unsigned want = (unsigned)t & 0xffffu;
      const unsigned* nsb = nslab + (t & 1) * NBS;
      unsigned v;
      for (;;) {
        v = (l < NBS) ? LD_RLX(nsb + l) : want;
        if (__all((int)((v & 0xffffu) == want))) break;
        __builtin_amdgcn_s_sleep(1);
      }
      float ns = (l < NBS) ? unpackf16(v) : 0.f;
      ns += __shfl_xor(ns, 1, 64);
      ns += __shfl_xor(ns, 2, 64);
      ns += __shfl_xor(ns, 4, 64);
      if (l == 0) invS = __builtin_amdgcn_rcpf(ns + 1e-5f);
    }
    __syncthreads();  // B2: invS visible
    const float inv = invS;

    // ---- phase 5: epilogue z = aX + inv*aC + b ----
    if (!isO) {
      const float* xmtp = xm + (size_t)t * 4096;
      float contrib[4][4];
#pragma unroll
      for (int ht = 0; ht < 4; ++ht)
#pragma unroll
        for (int rr = 0; rr < 4; ++rr) contrib[ht][rr] = 0.f;
#pragma unroll
      for (int un = 0; un < 2; ++un) {
        const int u = us * 16 + 2 * w + un;
        const bool isI = (u < 32);
        const int kidx = u - 32;
#pragma unroll
        for (int rr = 0; rr < 4; ++rr) {
          const int b = lk * 4 + rr;
          float s4[4], sum = 0.f;
#pragma unroll
          for (int ht = 0; ht < 4; ++ht) {
            float z = aX[un][ht][rr] + inv * aC[un][ht][rr] + bu[un][ht];
            float sg = __builtin_amdgcn_rcpf(1.0f + __expf(-z));
            s4[ht] = sg;
            sum += sg;
          }
          float r4 = sum;
          r4 += __shfl_xor(r4, 1, 64);
          r4 += __shfl_xor(r4, 2, 64);
          r4 += __shfl_xor(r4, 4, 64);
          r4 += __shfl_xor(r4, 8, 64);
          float wr = isI ? xmtp[(size_t)(bs * 16 + b) * 32 + u] : f16bits(craw[b][kidx]);
          float sc = wr * __builtin_amdgcn_rcpf(fmaxf(r4, 1e-12f));
#pragma unroll
          for (int ht = 0; ht < 4; ++ht) contrib[ht][rr] += s4[ht] * sc;
        }
      }
#pragma unroll
      for (int ht = 0; ht < 4; ++ht)
#pragma unroll
        for (int rr = 0; rr < 4; ++rr)
          pslab[w][(lk * 4 + rr) * 64 + ht * 16 + lr] = contrib[ht][rr];
    } else if (w == 0) {
#pragma unroll
      for (int ht = 0; ht < 4; ++ht)
#pragma unroll
        for (int rr = 0; rr < 4; ++rr) {
          float z = aX[0][ht][rr] + inv * aC[0][ht][rr] + bu[0][ht];
          pslab[0][(lk * 4 + rr) * 64 + ht * 16 + lr] =
              __builtin_amdgcn_rcpf(1.0f + __expf(-z));
        }
    }
    __syncthreads();  // B3: pslab complete

    // ---- phase 6: intra-WG sum -> coalesced tagged column store ----
    {
      const int e0 = 2 * tid;
      float v0, v1;
      if (!isO) {
        v0 = 0.f; v1 = 0.f;
#pragma unroll
        for (int p = 0; p < 8; ++p) {
          float2 pv2 = *(const float2*)&pslab[p][e0];
          v0 += pv2.x;
          v1 += pv2.y;
        }
      } else {
        float2 pv2 = *(const float2*)&pslab[0][e0];
        v0 = pv2.x;
        v1 = pv2.y;
      }
      const unsigned tg = (unsigned)(t + 1);
      unsigned* dst = slab + ((size_t)((t + 1) & 1) * NBS + bs) * (NUS * 1024) + us * 1024;
      ST_RLX(dst + e0, packf16(v0, tg));
      ST_RLX(dst + e0 + 1, packf16(v1, tg));
    }
    __syncthreads();  // B4: WAR (craw reads in phase 5 vs next phase-1 writes)
  }
}

extern "C" void kernel_launch(void* const* d_in, const int* in_sizes, int n_in,
                              void* d_out, int out_size, void* d_ws, size_t ws_size,
                              hipStream_t stream) {
  (void)in_sizes; (void)n_in; (void)out_size; (void)ws_size;
  const float* xm = (const float*)d_in[0];
  const float* xa = (const float*)d_in[1];
  const float* Wi = (const float*)d_in[2];
  const float* bi = (const float*)d_in[3];
  const float* Wr = (const float*)d_in[4];
  const float* br = (const float*)d_in[5];
  const float* Wo = (const float*)d_in[6];
  const float* bo = (const float*)d_in[7];

  char* ws = (char*)d_ws;
  f16* Wh         = (f16*)(ws + OFF_WH);
  unsigned* slab  = (unsigned*)(ws + OFF_SLAB);
  unsigned* nslab = (unsigned*)(ws + OFF_NS);

  // Tag hygiene across graph replays (stale tags would alias this run's wants).
  hipMemsetAsync(ws + ZERO_OFF, 0, ZERO_LEN, stream);
  prep_kernel<<<(97 * 8192 + 255) / 256, 256, 0, stream>>>(Wi, Wr, Wo, Wh);
  mclstm_kernel<<<NWG, 512, 0, stream>>>(xm, xa, bi, br, bo, Wh, slab, nslab,
                                         (float*)d_out);
}